// Round 3
// baseline (122.310 us; speedup 1.0000x reference)
//
#include <hip/hip_runtime.h>
#include <math.h>

#define IMG  128
#define NCH  64
#define PADC 4
#define PADW 136               // 128 + 2*4
#define PLANE (PADW * PADW)    // 18496
#define NPIX (IMG * IMG)       // 16384

// H = x-boxed correlation summed over ALL channels: [b][49][130][128]
#define HPH 130
#define HPW 128
#define HPLANE (HPH * HPW)     // 16640

// border-zero bookkeeping
#define PHI_THREADS   131072                // 2*4*128*128 compute threads (16 oc each)
#define PHI_BPP       2112                  // phi border floats per plane
#define PHI_BTOTAL    (128 * PHI_BPP)       // 270336
#define HB_TOTAL      (98 * 256)            // 25088: H rows 0,129 per 98 planes
#define TOTAL_THREADS (PHI_THREADS + PHI_BTOTAL + HB_TOTAL)  // 426496 = 1666*256

// ---------------------------------------------------------------------------
// K1: phi[b][c][y][x] = sum_i w[c][i]*u[b][i][y][x] into padded planes.
// Trailing blocks zero phi pad borders and H row-borders (rows 0,129).
// ---------------------------------------------------------------------------
__global__ __launch_bounds__(256) void k_phi(const float* __restrict__ u,
                                             const float* __restrict__ w,
                                             float* __restrict__ phi,
                                             float* __restrict__ H) {
  int t = blockIdx.x * 256 + threadIdx.x;

  if (t < PHI_THREADS) {
    int x  = t & 127;
    int y  = (t >> 7) & 127;
    int oc = (t >> 14) & 3;      // 4 groups of 16 output channels
    int b  = t >> 16;

    const float* up = u + (size_t)(b * NCH) * NPIX + y * IMG + x;
    const float* wr = w + oc * 16 * NCH;

    float acc[16];
#pragma unroll
    for (int k = 0; k < 16; ++k) acc[k] = 0.f;

#pragma unroll 8
    for (int i = 0; i < NCH; ++i) {
      float uv = up[(size_t)i * NPIX];
#pragma unroll
      for (int k = 0; k < 16; ++k) acc[k] += wr[k * NCH + i] * uv;
    }

    float* pp = phi + (size_t)(b * NCH + oc * 16) * PLANE + (y + PADC) * PADW + (x + PADC);
#pragma unroll
    for (int k = 0; k < 16; ++k) pp[(size_t)k * PLANE] = acc[k];
  } else if (t < PHI_THREADS + PHI_BTOTAL) {
    // phi border: rows 0..3,132..135 (all cols) + cols 0..3,132..135 (rows 4..131)
    int j = t - PHI_THREADS;
    int plane = j / PHI_BPP;
    int idx   = j - plane * PHI_BPP;
    int r, c;
    if (idx < 1088) { r = idx / 136; c = idx - (r * 136); r = (r < 4) ? r : r + 128; }
    else { int k = idx - 1088; r = (k >> 3) + 4; c = k & 7; c = (c < 4) ? c : c + 128; }
    phi[(size_t)plane * PLANE + r * PADW + c] = 0.f;
  } else if (t < TOTAL_THREADS) {
    // H border: rows 0 and 129 of each of 98 planes (y-box halo = 0)
    int j = t - (PHI_THREADS + PHI_BTOTAL);
    int plane = j >> 8;
    int idx   = j & 255;
    int r = (idx < 128) ? 0 : 129;
    int c = idx & 127;
    H[(size_t)plane * HPLANE + r * HPW + c] = 0.f;
  }
}

// ---------------------------------------------------------------------------
// K2: fused correlation + x-box over ALL 64 channels (part-fold: H and
// k_score reads halve). Block = 224 threads (8xq x 4y x 7dy) so all 7 dy
// share the same 10 phi rows through L1 (~1.6 KB/ch footprint vs 21.5 KB
// issued -> ~13x L1 reuse, L2/L3-side traffic 124 MB -> ~27 MB).
// Grid = 256 blocks (4 x-quarters x 32 y-bands x 2 b) = 1 block/CU.
// Emits hsum(x) = C(x-1)+C(x)+C(x+1) for 4 px in registers -> H.
// x/y out-of-image C values are exact zeros via phi's zero borders.
// ---------------------------------------------------------------------------
__global__ __launch_bounds__(224) void k_ch(const float* __restrict__ phi,
                                            float* __restrict__ H) {
  int tid  = threadIdx.x;          // 0..223
  int xq   = tid & 7;              // 8 groups of 4 px
  int yi   = (tid >> 3) & 3;       // row within 4-row band
  int dyI  = tid >> 5;             // 0..6
  int bid  = blockIdx.x;           // 0..255
  int xh   = bid & 3;              // x-quarter (32 px)
  int yb   = (bid >> 2) & 31;      // y-band
  int b    = bid >> 7;

  int x0 = xh * 32 + xq * 4;
  int y  = yb * 4 + yi;
  int dy = dyI - 3;

  const float* pb  = phi + (size_t)(b * NCH) * PLANE;
  const float* own = pb + (y + PADC) * PADW + x0;        // real cols x0-4..
  const float* nb  = pb + (y + dy + PADC) * PADW + x0;   // real cols x0-4..

  float acc[6][7];
#pragma unroll
  for (int p = 0; p < 6; ++p)
#pragma unroll
    for (int dxi = 0; dxi < 7; ++dxi) acc[p][dxi] = 0.f;

#pragma unroll 2
  for (int c = 0; c < NCH; ++c) {
    const float* oc_ = own + (size_t)c * PLANE;
    const float* nc_ = nb + (size_t)c * PLANE;
    float4 o0 = *(const float4*)(oc_);
    float4 o1 = *(const float4*)(oc_ + 4);
    float4 o2 = *(const float4*)(oc_ + 8);
    float4 n0 = *(const float4*)(nc_);
    float4 n1 = *(const float4*)(nc_ + 4);
    float4 n2 = *(const float4*)(nc_ + 8);
    float ov[12] = {o0.x, o0.y, o0.z, o0.w, o1.x, o1.y, o1.z, o1.w,
                    o2.x, o2.y, o2.z, o2.w};
    float nv[12] = {n0.x, n0.y, n0.z, n0.w, n1.x, n1.y, n1.z, n1.w,
                    n2.x, n2.y, n2.z, n2.w};
    // C(px = x0-1+p, dx = dxi-3): own idx p+3, nb idx p+dxi
#pragma unroll
    for (int p = 0; p < 6; ++p)
#pragma unroll
      for (int dxi = 0; dxi < 7; ++dxi)
        acc[p][dxi] += ov[p + 3] * nv[p + dxi];
  }

  float* base = H + (size_t)b * 49 * HPLANE;
#pragma unroll
  for (int dxi = 0; dxi < 7; ++dxi) {
    int d = dyI * 7 + dxi;
    // hsum at x0+j = C(x0+j-1)+C(x0+j)+C(x0+j+1) = acc[j]+acc[j+1]+acc[j+2]
    float h0 = acc[0][dxi] + acc[1][dxi] + acc[2][dxi];
    float h1 = acc[1][dxi] + acc[2][dxi] + acc[3][dxi];
    float h2 = acc[2][dxi] + acc[3][dxi] + acc[4][dxi];
    float h3 = acc[3][dxi] + acc[4][dxi] + acc[5][dxi];
    float* dst = base + ((size_t)d * HPH + (y + 1)) * HPW + x0;
    *(float4*)dst = make_float4(h0, h1, h2, h3);
  }
}

// ---------------------------------------------------------------------------
// K3: s[d] = mask * sum_{ry=-1..1} H_d(y+ry, x); softmax over 49; coalesced
// store via LDS. 4-way d-sliced: block = 256 threads / 64 px (2048 waves),
// LDS max/sum combine. Part loop gone -> reads halved vs round 2.
// ---------------------------------------------------------------------------
__global__ __launch_bounds__(256) void k_score(const float* __restrict__ H,
                                               float* __restrict__ out) {
  __shared__ float sdat[64 * 49];
  __shared__ float rmax[4][64];
  __shared__ float rsum[4][64];
  int tid   = threadIdx.x;
  int px    = tid & 63;
  int slice = tid >> 6;
  int g = blockIdx.x * 64 + px;     // linear pixel; 64 | 128 -> whole block same y
  int x = g & 127;
  int y = (g >> 7) & 127;
  int b = g >> 14;

  // slice handles d = slice, slice+4, ... (13 for slice 0, else 12)
  float sv[13];
  float pm = -1e30f;
#pragma unroll
  for (int i = 0; i < 13; ++i) {
    int d = slice + 4 * i;
    if (d < 49) {
      int dyI = (d * 37) >> 8;      // d/7 for d<49
      int dxi = d - dyI * 7;
      const float* hb = H + ((size_t)(b * 49 + d) * HPH + y) * HPW + x;
      float v = hb[0] + hb[HPW] + hb[2 * HPW];   // H rows y..y+2 = C rows y-1..y+1
      int qy = y + dyI - 3, qx = x + dxi - 3;
      v = ((unsigned)qy < 128u && (unsigned)qx < 128u) ? v : 0.f;
      sv[i] = v;
      pm = fmaxf(pm, v);
    }
  }
  rmax[slice][px] = pm;
  __syncthreads();
  float m = fmaxf(fmaxf(rmax[0][px], rmax[1][px]),
                  fmaxf(rmax[2][px], rmax[3][px]));

  float ps = 0.f;
#pragma unroll
  for (int i = 0; i < 13; ++i) {
    int d = slice + 4 * i;
    if (d < 49) {
      float e = __expf(sv[i] - m);
      sv[i] = e;
      ps += e;
    }
  }
  rsum[slice][px] = ps;
  __syncthreads();
  float inv = 1.f / (rsum[0][px] + rsum[1][px] + rsum[2][px] + rsum[3][px]);

#pragma unroll
  for (int i = 0; i < 13; ++i) {
    int d = slice + 4 * i;
    if (d < 49) sdat[px * 49 + d] = sv[i] * inv;
  }
  __syncthreads();

  // block's out chunk = 64*49 = 3136 contiguous floats = 784 float4
  float* ob = out + (size_t)blockIdx.x * (64 * 49);
  const float4* l4 = (const float4*)sdat;
#pragma unroll
  for (int i = 0; i < 3; ++i)                 // 3*256 = 768 float4
    ((float4*)ob)[i * 256 + tid] = l4[i * 256 + tid];
  if (tid < 16)                               // remaining 16 float4
    ((float4*)ob)[768 + tid] = l4[768 + tid];
}

// ---------------------------------------------------------------------------
extern "C" void kernel_launch(void* const* d_in, const int* in_sizes, int n_in,
                              void* d_out, int out_size, void* d_ws, size_t ws_size,
                              hipStream_t stream) {
  const float* u = (const float*)d_in[0];
  const float* w = (const float*)d_in[1];
  float* out = (float*)d_out;

  float* phi = (float*)d_ws;                           // 2*64*18496 = 2367488 floats
  float* H   = phi + (size_t)2 * NCH * PLANE;          // 2*49*16640 = 1630720 floats

  k_phi  <<<TOTAL_THREADS / 256, 256, 0, stream>>>(u, w, phi, H);
  k_ch   <<<256, 224, 0, stream>>>(phi, H);
  k_score<<<512, 256, 0, stream>>>(H, out);
}

// Round 4
// 104.083 us; speedup vs baseline: 1.1751x; 1.1751x over previous
//
#include <hip/hip_runtime.h>
#include <math.h>

#define IMG  128
#define NCH  64
#define PADC 4
#define PADW 136               // 128 + 2*4
#define PLANE (PADW * PADW)    // 18496
#define NPIX (IMG * IMG)       // 16384

// H = x-boxed correlation, planes [part][b][49][130][128]; row r <-> C row r-1
#define HPH 130
#define HPW 128
#define HPLANE (HPH * HPW)     // 16640

// border-zero bookkeeping
#define PHI_THREADS   131072                // 2*4*128*128 compute threads (16 oc each)
#define PHI_BPP       2112                  // phi border floats per plane
#define PHI_BTOTAL    (128 * PHI_BPP)       // 270336
#define HB_TOTAL      (196 * 256)           // 50176: H rows 0,129 per 196 planes
#define TOTAL_THREADS (PHI_THREADS + PHI_BTOTAL + HB_TOTAL)  // 451584

// ---------------------------------------------------------------------------
// K1: phi[b][c][y][x] = sum_i w[c][i]*u[b][i][y][x] into padded planes.
// Trailing blocks zero phi pad borders and H row-borders (rows 0,129).
// ---------------------------------------------------------------------------
__global__ __launch_bounds__(256) void k_phi(const float* __restrict__ u,
                                             const float* __restrict__ w,
                                             float* __restrict__ phi,
                                             float* __restrict__ H) {
  int t = blockIdx.x * 256 + threadIdx.x;

  if (t < PHI_THREADS) {
    int x  = t & 127;
    int y  = (t >> 7) & 127;
    int oc = (t >> 14) & 3;      // 4 groups of 16 output channels
    int b  = t >> 16;

    const float* up = u + (size_t)(b * NCH) * NPIX + y * IMG + x;
    const float* wr = w + oc * 16 * NCH;

    float acc[16];
#pragma unroll
    for (int k = 0; k < 16; ++k) acc[k] = 0.f;

#pragma unroll 8
    for (int i = 0; i < NCH; ++i) {
      float uv = up[(size_t)i * NPIX];
#pragma unroll
      for (int k = 0; k < 16; ++k) acc[k] += wr[k * NCH + i] * uv;
    }

    float* pp = phi + (size_t)(b * NCH + oc * 16) * PLANE + (y + PADC) * PADW + (x + PADC);
#pragma unroll
    for (int k = 0; k < 16; ++k) pp[(size_t)k * PLANE] = acc[k];
  } else if (t < PHI_THREADS + PHI_BTOTAL) {
    // phi border: rows 0..3,132..135 (all cols) + cols 0..3,132..135 (rows 4..131)
    int j = t - PHI_THREADS;
    int plane = j / PHI_BPP;
    int idx   = j - plane * PHI_BPP;
    int r, c;
    if (idx < 1088) { r = idx / 136; c = idx - (r * 136); r = (r < 4) ? r : r + 128; }
    else { int k = idx - 1088; r = (k >> 3) + 4; c = k & 7; c = (c < 4) ? c : c + 128; }
    phi[(size_t)plane * PLANE + r * PADW + c] = 0.f;
  } else if (t < TOTAL_THREADS) {
    // H border: rows 0 and 129 of each of 196 planes (y-box halo = 0)
    int j = t - (PHI_THREADS + PHI_BTOTAL);
    int plane = j >> 8;
    int idx   = j & 255;
    int r = (idx < 128) ? 0 : 129;
    int c = idx & 127;
    H[(size_t)plane * HPLANE + r * HPW + c] = 0.f;
  }
}

// ---------------------------------------------------------------------------
// K2: fused correlation + x-box. Thread = (part[2], b, dy, y, 4-px group).
// Computes C_d for 6 px (x0-1..x0+4) x 7 dx over a 32-ch half, then emits
// hsum(x) = C(x-1)+C(x)+C(x+1) for 4 px entirely in registers -> H.
// 114688 threads = 7 waves/CU, 448 blocks. (Round-3 lesson: folding parts
// into the thread halves occupancy to 3.5 waves/CU and regresses 3x —
// this latency-bound kernel needs the 7-wave shape.)
// x/y out-of-image C values are exact zeros via phi's zero borders.
// ---------------------------------------------------------------------------
__global__ __launch_bounds__(256) void k_ch(const float* __restrict__ phi,
                                            float* __restrict__ H) {
  int t   = blockIdx.x * 256 + threadIdx.x;  // 2*2*7*128*32 = 114688
  int xq  = t & 31;
  int y   = (t >> 5) & 127;
  int r   = t >> 12;            // 0..27 = part*14 + b*7 + dyI
  int part = r / 14;
  int rr   = r - part * 14;
  int b    = rr / 7;
  int dyI  = rr - b * 7;
  int x0   = xq * 4;
  int dy   = dyI - 3;

  const float* pb  = phi + (size_t)(b * NCH + part * 32) * PLANE;
  const float* own = pb + (y + PADC) * PADW + x0;        // real cols x0-4..
  const float* nb  = pb + (y + dy + PADC) * PADW + x0;   // real cols x0-4..

  float acc[6][7];
#pragma unroll
  for (int p = 0; p < 6; ++p)
#pragma unroll
    for (int dxi = 0; dxi < 7; ++dxi) acc[p][dxi] = 0.f;

#pragma unroll 2
  for (int c = 0; c < 32; ++c) {
    const float* oc_ = own + (size_t)c * PLANE;
    const float* nc_ = nb + (size_t)c * PLANE;
    float4 o0 = *(const float4*)(oc_);
    float4 o1 = *(const float4*)(oc_ + 4);
    float4 o2 = *(const float4*)(oc_ + 8);
    float4 n0 = *(const float4*)(nc_);
    float4 n1 = *(const float4*)(nc_ + 4);
    float4 n2 = *(const float4*)(nc_ + 8);
    float ov[12] = {o0.x, o0.y, o0.z, o0.w, o1.x, o1.y, o1.z, o1.w,
                    o2.x, o2.y, o2.z, o2.w};
    float nv[12] = {n0.x, n0.y, n0.z, n0.w, n1.x, n1.y, n1.z, n1.w,
                    n2.x, n2.y, n2.z, n2.w};
    // C(px = x0-1+p, dx = dxi-3): own idx p+3, nb idx p+dxi
#pragma unroll
    for (int p = 0; p < 6; ++p)
#pragma unroll
      for (int dxi = 0; dxi < 7; ++dxi)
        acc[p][dxi] += ov[p + 3] * nv[p + dxi];
  }

  float* base = H + (size_t)(part * 2 + b) * 49 * HPLANE;
#pragma unroll
  for (int dxi = 0; dxi < 7; ++dxi) {
    int d = dyI * 7 + dxi;
    // hsum at x0+j = C(x0+j-1)+C(x0+j)+C(x0+j+1) = acc[j]+acc[j+1]+acc[j+2]
    float h0 = acc[0][dxi] + acc[1][dxi] + acc[2][dxi];
    float h1 = acc[1][dxi] + acc[2][dxi] + acc[3][dxi];
    float h2 = acc[2][dxi] + acc[3][dxi] + acc[4][dxi];
    float h3 = acc[3][dxi] + acc[4][dxi] + acc[5][dxi];
    float* dst = base + ((size_t)d * HPH + (y + 1)) * HPW + x0;
    *(float4*)dst = make_float4(h0, h1, h2, h3);
  }
}

// ---------------------------------------------------------------------------
// K3: s[d] = mask * sum_{part} sum_{ry=-1..1} H_d(y+ry, x); softmax over 49;
// coalesced store via LDS. 4-way d-sliced: block = 256 threads / 64 px
// (2048 waves -> 2 waves/SIMD), LDS max/sum combine.
// ---------------------------------------------------------------------------
__global__ __launch_bounds__(256) void k_score(const float* __restrict__ H,
                                               float* __restrict__ out) {
  __shared__ float sdat[64 * 49];
  __shared__ float rmax[4][64];
  __shared__ float rsum[4][64];
  int tid   = threadIdx.x;
  int px    = tid & 63;
  int slice = tid >> 6;
  int g = blockIdx.x * 64 + px;     // linear pixel; 64 | 128 -> whole block same y
  int x = g & 127;
  int y = (g >> 7) & 127;
  int b = g >> 14;

  // slice handles d = slice, slice+4, ... (13 for slice 0, else 12)
  float sv[13];
  float pm = -1e30f;
#pragma unroll
  for (int i = 0; i < 13; ++i) {
    int d = slice + 4 * i;
    if (d < 49) {
      int dyI = (d * 37) >> 8;      // d/7 for d<49
      int dxi = d - dyI * 7;
      float v = 0.f;
#pragma unroll
      for (int part = 0; part < 2; ++part) {
        const float* hb = H + ((size_t)((part * 2 + b) * 49 + d) * HPH + y) * HPW + x;
        v += hb[0] + hb[HPW] + hb[2 * HPW];   // H rows y..y+2 = C rows y-1..y+1
      }
      int qy = y + dyI - 3, qx = x + dxi - 3;
      v = ((unsigned)qy < 128u && (unsigned)qx < 128u) ? v : 0.f;
      sv[i] = v;
      pm = fmaxf(pm, v);
    }
  }
  rmax[slice][px] = pm;
  __syncthreads();
  float m = fmaxf(fmaxf(rmax[0][px], rmax[1][px]),
                  fmaxf(rmax[2][px], rmax[3][px]));

  float ps = 0.f;
#pragma unroll
  for (int i = 0; i < 13; ++i) {
    int d = slice + 4 * i;
    if (d < 49) {
      float e = __expf(sv[i] - m);
      sv[i] = e;
      ps += e;
    }
  }
  rsum[slice][px] = ps;
  __syncthreads();
  float inv = 1.f / (rsum[0][px] + rsum[1][px] + rsum[2][px] + rsum[3][px]);

#pragma unroll
  for (int i = 0; i < 13; ++i) {
    int d = slice + 4 * i;
    if (d < 49) sdat[px * 49 + d] = sv[i] * inv;
  }
  __syncthreads();

  // block's out chunk = 64*49 = 3136 contiguous floats = 784 float4
  float* ob = out + (size_t)blockIdx.x * (64 * 49);
  const float4* l4 = (const float4*)sdat;
#pragma unroll
  for (int i = 0; i < 3; ++i)                 // 3*256 = 768 float4
    ((float4*)ob)[i * 256 + tid] = l4[i * 256 + tid];
  if (tid < 16)                               // remaining 16 float4
    ((float4*)ob)[768 + tid] = l4[768 + tid];
}

// ---------------------------------------------------------------------------
extern "C" void kernel_launch(void* const* d_in, const int* in_sizes, int n_in,
                              void* d_out, int out_size, void* d_ws, size_t ws_size,
                              hipStream_t stream) {
  const float* u = (const float*)d_in[0];
  const float* w = (const float*)d_in[1];
  float* out = (float*)d_out;

  float* phi = (float*)d_ws;                           // 2*64*18496 = 2367488 floats
  float* H   = phi + (size_t)2 * NCH * PLANE;          // 2*2*49*16640 = 3261440 floats

  k_phi  <<<TOTAL_THREADS / 256, 256, 0, stream>>>(u, w, phi, H);
  k_ch   <<<448, 256, 0, stream>>>(phi, H);
  k_score<<<512, 256, 0, stream>>>(H, out);
}